// Round 16
// baseline (373.515 us; speedup 1.0000x reference)
//
#include <hip/hip_runtime.h>

#define DEV __device__ __forceinline__

typedef __attribute__((ext_vector_type(8))) short bf16x8;
typedef __attribute__((ext_vector_type(4))) float f32x4;

DEV float4 ld4(const float* p){ return *reinterpret_cast<const float4*>(p); }

DEV unsigned short f2bf(float f){
    union { float f; unsigned u; } v; v.f = f;
    unsigned r = v.u + 0x7fffu + ((v.u >> 16) & 1u);   // RNE
    return (unsigned short)(r >> 16);
}
DEV float bf2f(unsigned short s){
    union { unsigned u; float f; } v; v.u = ((unsigned)s) << 16;
    return v.f;
}

// async global->LDS, 16B/lane: LDS dest wave-uniform base + lane*16, global SOURCE per-lane.
DEV void async16(const void* g, void* l){
    __builtin_amdgcn_global_load_lds(
        (const __attribute__((address_space(1))) unsigned*)g,
        (__attribute__((address_space(3))) unsigned*)l, 16, 0, 0);
}

// bijective XCD-chunk swizzle (m204)
DEV int xcd_swizzle(int orig, int nwg){
    int q = nwg >> 3, r = nwg & 7;
    int x = orig & 7, i = orig >> 3;
    return (x < r ? x*(q+1) : r*(q+1) + (x-r)*q) + i;
}

// ---------------- inverse kernel-map build ----------------
__global__ __launch_bounds__(256)
void inv_init(int* __restrict__ inv, long n, int defv){
    long i = (long)blockIdx.x*256 + threadIdx.x;
    if (i < n) inv[i] = defv;
}

__global__ __launch_bounds__(256)
void inv_build(const int* __restrict__ inK, const int* __restrict__ outK,
               int* __restrict__ inv, int M, int n_out){
    int k = blockIdx.y;
    int m = blockIdx.x*256 + threadIdx.x;
    if (m >= M) return;
    int o = outK[(long)k*M + m];
    if (o != n_out) inv[(long)k*n_out + o] = inK[(long)k*M + m];  // o unique per offset
}

// zero sentinel rows: A/B/C/D/E row n_out; Z row n_in
__global__ __launch_bounds__(256)
void zero_rows(unsigned short* A, unsigned short* B, unsigned short* C,
               unsigned short* D, unsigned short* E, unsigned short* Z,
               int n_out, int n_in){
    int t = threadIdx.x;
    if (t < 64)       A[(long)n_out*64 + t] = 0;
    else if (t < 80)  B[(long)n_out*16 + (t-64)] = 0;
    else if (t < 144) C[(long)n_out*64 + (t-80)] = 0;
    else if (t < 160) D[(long)n_out*16 + (t-144)] = 0;
    else if (t < 176) E[(long)n_out*16 + (t-160)] = 0;
    else if (t < 240) Z[(long)n_in*64 + (t-176)] = 0;
}

// ---------------- W -> fragment-layout bf16 conversion ----------------
__global__ __launch_bounds__(256)
void wfrag_unpaired(const float* __restrict__ W, unsigned short* __restrict__ F,
                    int KC, int NT, int CIN, int CR, int total){
    int idx = blockIdx.x*256 + threadIdx.x;
    if (idx >= total) return;
    int j = idx & 7, l = (idx >> 3) & 63, rest = idx >> 9;
    int nt = rest % NT, cc = rest / NT;
    int k = cc / KC, kc = cc % KC;
    int g = l >> 4, c = l & 15;
    int cin = kc*32 + g*8 + j, cout = nt*16 + c;
    float v = (cout < CR) ? W[((long)k*CIN + cin)*CR + cout] : 0.f;
    F[idx] = f2bf(v);
}

__global__ __launch_bounds__(256)
void wfrag_paired(const float* __restrict__ W, unsigned short* __restrict__ F,
                  int NKr, int NT, int CR, int total){
    int idx = blockIdx.x*256 + threadIdx.x;
    if (idx >= total) return;
    int j = idx & 7, l = (idx >> 3) & 63, rest = idx >> 9;
    int nt = rest % NT, cc = rest / NT;
    int g = l >> 4, c = l & 15;
    int koff = 2*cc + (g >> 1);
    int cin = (g & 1)*8 + j, cout = nt*16 + c;
    float v = (koff < NKr && cout < CR) ? W[((long)koff*16 + cin)*CR + cout] : 0.f;
    F[idx] = f2bf(v);
}

// ---------------- 27-offset gather conv: W-in-LDS + direct fragment gather ----------------
// Block = 4 waves x 16 rows = 64 rows. Whole Wf (54 chunks x 1KB = 55296 B) staged to LDS once
// per block (linear global_load_lds), then per-k W comes from ds_read (no TA work). Features
// gather DIRECTLY into the MFMA A-fragment: lane (r,g) loads 16B at X[b_r]*128 + {0,64} + g*16
// (unconditional; sentinel -> zero row). idx is one broadcast line per wave per k, carried
// 2-deep; features/W prefetched 1-deep. No staging LDS, no loop barriers.
template<bool RELU, bool OUTBF16, int YS, int CR>
__global__ __launch_bounds__(256)
void gather27_direct(const void* __restrict__ Xv, const unsigned short* __restrict__ Wf,
                     const int* __restrict__ inv, const float* __restrict__ bias,
                     void* __restrict__ Yv, int n_out)
{
    __shared__ alignas(16) unsigned short wlds[54*512];   // 55296 B
    const int lane = threadIdx.x & 63, w = threadIdx.x >> 6;
    const int bid = xcd_swizzle(blockIdx.x, gridDim.x);
    const long jblock = (long)bid * 64;
    const int r = lane & 15, g = lane >> 4;
    const char* X = (const char*)Xv;
    char* WL = (char*)wlds;

    // stage Wf -> LDS (linear; dest wave-uniform + lane*16)
    #pragma unroll
    for (int it = 0; it < 14; ++it){
        int slot = it*256 + threadIdx.x;
        if (slot < 3456)
            async16((const char*)Wf + (long)slot*16, WL + it*4096 + w*1024);
    }
    __syncthreads();   // drains the DMA

    const long jr = min(jblock + w*16 + r, (long)n_out - 1);
    f32x4 acc = {0,0,0,0};

    // prologue: idx(0) -> features(0); idx(1), idx(2); W(0)
    int b0 = inv[jr];
    bf16x8 a0 = *(const bf16x8*)(X + (long)b0*128 +      g*16);
    bf16x8 a1 = *(const bf16x8*)(X + (long)b0*128 + 64 + g*16);
    int b1 = inv[(long)n_out + jr];
    int b2 = inv[(long)2*n_out + jr];
    bf16x8 w0 = *(const bf16x8*)(WL + 0*1024 + lane*16);
    bf16x8 w1 = *(const bf16x8*)(WL + 1*1024 + lane*16);

    #pragma unroll 1
    for (int k = 0; k < 27; ++k){
        // idx(k+3), 2-deep carry
        int bn = 0;
        if (k + 3 < 27) bn = inv[(long)(k+3)*n_out + jr];
        // features(k+1) from b1 (loaded 2 iterations ago)
        bf16x8 na0 = a0, na1 = a1, nw0 = w0, nw1 = w1;
        if (k < 26){
            na0 = *(const bf16x8*)(X + (long)b1*128 +      g*16);
            na1 = *(const bf16x8*)(X + (long)b1*128 + 64 + g*16);
            nw0 = *(const bf16x8*)(WL + (long)(2*(k+1)  )*1024 + lane*16);
            nw1 = *(const bf16x8*)(WL + (long)(2*(k+1)+1)*1024 + lane*16);
        }
        acc = __builtin_amdgcn_mfma_f32_16x16x32_bf16(a0, w0, acc, 0, 0, 0);
        acc = __builtin_amdgcn_mfma_f32_16x16x32_bf16(a1, w1, acc, 0, 0, 0);
        a0 = na0; a1 = na1; w0 = nw0; w1 = nw1;
        b1 = b2; b2 = bn;
    }

    // epilogue: D layout col = lane&15, row = (lane>>4)*4 + q
    const float bv = (r < CR) ? bias[r] : 0.f;
    #pragma unroll
    for (int q = 0; q < 4; ++q){
        long row = jblock + w*16 + g*4 + q;
        if (row < n_out){
            float v = acc[q] + bv;
            if constexpr (RELU) v = fmaxf(v, 0.f);
            if constexpr (OUTBF16) ((unsigned short*)Yv)[row*YS + r] = f2bf(v);
            else if (r < CR)       ((float*)Yv)[row*YS + r] = v;
        }
    }
}

// ---------------- conv1 phase 1: Z[i] = x_cat[i] @ W1[kid(i)] — hoisted loads ----------------
__global__ __launch_bounds__(256, 8)
void conv1_z(const float* __restrict__ xF, const float* __restrict__ cF,
             const unsigned short* __restrict__ Wfc1, const int* __restrict__ in1,
             unsigned short* __restrict__ Z, int M1, int n_in)
{
    __shared__ unsigned short tz[4][16*64];
    const int k = blockIdx.x;
    const int lane = threadIdx.x & 63, wave = threadIdx.x >> 6;
    const int m0 = (blockIdx.y*4 + wave)*16;
    if (m0 >= M1) return;
    const int r = lane & 15, g = lane >> 4;
    const int* __restrict__ in1k = in1 + (long)k*M1;
    const int mc = min(m0 + r, M1-1);
    const int i = in1k[mc];
    const bool valid = i < n_in;             // pad sentinel = n_in
    const long iv = valid ? i : 0;
    const bf16x8* __restrict__ WF = (const bf16x8*)(Wfc1 + (size_t)k*16*512);
    const bf16x8 az = {0,0,0,0,0,0,0,0};
    f32x4 acc[4];
    #pragma unroll
    for (int nt=0; nt<4; ++nt) acc[nt] = f32x4{0,0,0,0};

    float4 lo[4], hi[4];
    #pragma unroll
    for (int kc=0; kc<4; ++kc){
        const float* s = (kc < 2) ? (xF + iv*64 + kc*32 + g*8)
                                  : (cF + iv*64 + (kc-2)*32 + g*8);
        lo[kc] = ld4(s);
        hi[kc] = ld4(s+4);
    }
    #pragma unroll
    for (int kc=0; kc<4; ++kc){
        bf16x8 a;
        a[0]=(short)f2bf(lo[kc].x); a[1]=(short)f2bf(lo[kc].y);
        a[2]=(short)f2bf(lo[kc].z); a[3]=(short)f2bf(lo[kc].w);
        a[4]=(short)f2bf(hi[kc].x); a[5]=(short)f2bf(hi[kc].y);
        a[6]=(short)f2bf(hi[kc].z); a[7]=(short)f2bf(hi[kc].w);
        if (!valid) a = az;
        #pragma unroll
        for (int nt=0; nt<4; ++nt){
            bf16x8 wv = WF[((long)kc*4 + nt)*64 + lane];
            acc[nt] = __builtin_amdgcn_mfma_f32_16x16x32_bf16(a, wv, acc[nt], 0, 0, 0);
        }
    }

    #pragma unroll
    for (int q=0; q<4; ++q)
        #pragma unroll
        for (int nt=0; nt<4; ++nt)
            tz[wave][(g*4+q)*64 + nt*16 + r] = f2bf(acc[nt][q]);
    __syncthreads();
    #pragma unroll
    for (int it=0; it<2; ++it){
        int cid = it*64 + lane;
        int row = cid >> 3, c8 = (cid & 7)*8;
        int m = m0 + row;
        if (m < M1){
            int oi = in1k[m];
            long drow = (oi < n_in) ? (long)oi : (long)n_in + 1;
            *(bf16x8*)(Z + drow*64 + c8) = *(const bf16x8*)(&tz[wave][row*64 + c8]);
        }
    }
}

// ---------------- conv1 phase 2: A[o] = b1 + sum_k Z[inv1[k][o]] ----------------
__global__ __launch_bounds__(256)
void conv1_sum(const unsigned short* __restrict__ Z, const int* __restrict__ inv1,
               const float* __restrict__ b1, unsigned short* __restrict__ A, int n_out)
{
    const int bid = xcd_swizzle(blockIdx.x, gridDim.x);
    const long t = (long)bid*256 + threadIdx.x;
    const long o = t >> 3;
    if (o >= n_out) return;
    const int c8 = (int)(t & 7) * 8;
    int b[8];
    #pragma unroll
    for (int k=0;k<8;++k) b[k] = inv1[(long)k*n_out + o];
    float acc[8];
    #pragma unroll
    for (int j=0;j<2;++j){
        float4 v = ld4(b1 + c8 + 4*j);
        acc[4*j]=v.x; acc[4*j+1]=v.y; acc[4*j+2]=v.z; acc[4*j+3]=v.w;
    }
    #pragma unroll
    for (int k=0;k<8;++k){
        bf16x8 z = *(const bf16x8*)(Z + (long)b[k]*64 + c8);
        #pragma unroll
        for (int j=0;j<8;++j) acc[j] += bf2f((unsigned short)z[j]);
    }
    bf16x8 outv;
    #pragma unroll
    for (int j=0;j<8;++j) outv[j] = (short)f2bf(acc[j]);
    *(bf16x8*)(A + o*64 + c8) = outv;
}

// ---------------- paired inv-gather (CIN=16) — validated form ----------------
template<int NK, int G, int NT, int RB, bool RELU, int RESBASE,
         int YS, int CB, int CR, int WPE>
__global__ __launch_bounds__(256, WPE)
void mfma_g1(const void* __restrict__ Xv, const unsigned short* __restrict__ Wf,
             const int* __restrict__ inv, const float* __restrict__ bias,
             const unsigned short* __restrict__ RES, unsigned short* __restrict__ Y, int n_out)
{
    const int lane = threadIdx.x & 63, wave = threadIdx.x >> 6;
    const int jbase = (blockIdx.x*4 + wave)*32;
    if (jbase >= n_out) return;
    const int r = lane & 15, g = lane >> 4;
    const int jc0 = min(jbase + r, n_out-1), jc1 = min(jbase + 16 + r, n_out-1);
    const char* X = (const char*)Xv;
    const bf16x8* __restrict__ WF = (const bf16x8*)Wf;
    f32x4 acc0[NT], acc1[NT];
    #pragma unroll
    for (int nt=0; nt<NT; ++nt){ acc0[nt] = f32x4{0,0,0,0}; acc1[nt] = f32x4{0,0,0,0}; }

    #pragma unroll 1
    for (int g0 = 0; g0 < NK; g0 += G) {
        int b0[G], b1[G];
        #pragma unroll
        for (int kk=0; kk<G; ++kk){
            int koff = 2*(g0+kk) + (g >> 1);
            b0[kk] = inv[(long)koff*n_out + jc0];
            b1[kk] = inv[(long)koff*n_out + jc1];
        }
        #pragma unroll
        for (int kk=0; kk<G; ++kk){
            const int k = g0 + kk;
            bf16x8 a0 = *(const bf16x8*)(X + (long)b0[kk]*RB + (g&1)*16);
            bf16x8 a1 = *(const bf16x8*)(X + (long)b1[kk]*RB + (g&1)*16);
            #pragma unroll
            for (int nt=0; nt<NT; ++nt){
                bf16x8 wv = WF[((long)k*NT + nt)*64 + lane];
                acc0[nt] = __builtin_amdgcn_mfma_f32_16x16x32_bf16(a0, wv, acc0[nt], 0, 0, 0);
                acc1[nt] = __builtin_amdgcn_mfma_f32_16x16x32_bf16(a1, wv, acc1[nt], 0, 0, 0);
            }
        }
    }

    float bi[NT];
    #pragma unroll
    for (int nt=0; nt<NT; ++nt){
        int c = nt*16 + r;
        bi[nt] = (c < CR) ? bias[c] : 0.f;
    }
    #pragma unroll
    for (int q=0; q<4; ++q){
        int row = jbase + g*4 + q;
        if (row < n_out){
            #pragma unroll
            for (int nt=0; nt<NT; ++nt){
                int c = nt*16 + r;
                float v = acc0[nt][q] + bi[nt];
                if constexpr (RESBASE >= 0) v += bf2f(RES[(long)row*64 + RESBASE + c]);
                if constexpr (RELU) v = fmaxf(v, 0.f);
                Y[(long)row*YS + CB + c] = f2bf(v);
            }
        }
        int row2 = jbase + 16 + g*4 + q;
        if (row2 < n_out){
            #pragma unroll
            for (int nt=0; nt<NT; ++nt){
                int c = nt*16 + r;
                float v = acc1[nt][q] + bi[nt];
                if constexpr (RESBASE >= 0) v += bf2f(RES[(long)row2*64 + RESBASE + c]);
                if constexpr (RELU) v = fmaxf(v, 0.f);
                Y[(long)row2*YS + CB + c] = f2bf(v);
            }
        }
    }
}

// ---------------- identity-mode MFMA (dense 1x1s) — validated form ----------------
template<int MODE, int NT, int RB, bool RELU, int RESBASE, int YS, int CB, int CR>
__global__ __launch_bounds__(256)
void mfma_dense(const void* __restrict__ Xv, const unsigned short* __restrict__ Wf,
                const float* __restrict__ bias, const unsigned short* __restrict__ RES,
                unsigned short* __restrict__ Y, int n_out)
{
    const int lane = threadIdx.x & 63, wave = threadIdx.x >> 6;
    const int jbase = (blockIdx.x*4 + wave)*16;
    if (jbase >= n_out) return;
    const int r = lane & 15, g = lane >> 4;
    const int jrow = jbase + r;
    const bool rowok = jrow < n_out;
    const char* X = (const char*)Xv;
    const bf16x8* __restrict__ WF = (const bf16x8*)Wf;
    const bf16x8 az = {0,0,0,0,0,0,0,0};
    f32x4 acc[NT];
    #pragma unroll
    for (int nt=0; nt<NT; ++nt) acc[nt] = f32x4{0,0,0,0};

    if constexpr (MODE == 2) {
        #pragma unroll
        for (int kc=0; kc<2; ++kc){
            bf16x8 a = az;
            if (rowok) a = *(const bf16x8*)(X + (long)jrow*RB + kc*64 + g*16);
            #pragma unroll
            for (int nt=0; nt<NT; ++nt){
                bf16x8 wv = WF[((long)kc*NT + nt)*64 + lane];
                acc[nt] = __builtin_amdgcn_mfma_f32_16x16x32_bf16(a, wv, acc[nt], 0, 0, 0);
            }
        }
    } else {
        bf16x8 a = az;
        if (rowok && g < 2) a = *(const bf16x8*)(X + (long)jrow*RB + (g&1)*16);
        #pragma unroll
        for (int nt=0; nt<NT; ++nt){
            bf16x8 wv = WF[nt*64 + lane];
            acc[nt] = __builtin_amdgcn_mfma_f32_16x16x32_bf16(a, wv, acc[nt], 0, 0, 0);
        }
    }

    float bi[NT];
    #pragma unroll
    for (int nt=0; nt<NT; ++nt){
        int c = nt*16 + r;
        bi[nt] = (c < CR) ? bias[c] : 0.f;
    }
    #pragma unroll
    for (int q=0; q<4; ++q){
        int row = jbase + g*4 + q;
        if (row < n_out){
            #pragma unroll
            for (int nt=0; nt<NT; ++nt){
                int c = nt*16 + r;
                float v = acc[nt][q] + bi[nt];
                if constexpr (RESBASE >= 0) v += bf2f(RES[(long)row*64 + RESBASE + c]);
                if constexpr (RELU) v = fmaxf(v, 0.f);
                Y[(long)row*YS + CB + c] = f2bf(v);
            }
        }
    }
}

extern "C" void kernel_launch(void* const* d_in, const int* in_sizes, int n_in_cnt,
                              void* d_out, int out_size, void* d_ws, size_t ws_size,
                              hipStream_t stream)
{
    const float* xF   = (const float*)d_in[0];
    const float* ctxF = (const float*)d_in[1];
    const float* W1   = (const float*)d_in[2];
    const float* b1   = (const float*)d_in[3];
    const float* Wr00 = (const float*)d_in[4];
    const float* br00 = (const float*)d_in[5];
    const float* Wr01 = (const float*)d_in[6];
    const float* br01 = (const float*)d_in[7];
    const float* Wr10 = (const float*)d_in[8];
    const float* br10 = (const float*)d_in[9];
    const float* Wr11 = (const float*)d_in[10];
    const float* br11 = (const float*)d_in[11];
    const float* Wr12 = (const float*)d_in[12];
    const float* br12 = (const float*)d_in[13];
    const float* W2   = (const float*)d_in[14];
    const float* b2   = (const float*)d_in[15];
    const int* in1  = (const int*)d_in[16];
    const int* out1 = (const int*)d_in[17];
    const int* in3  = (const int*)d_in[18];
    const int* out3 = (const int*)d_in[19];

    const int n_out = out_size / 8;          // CL = 8
    const int n_in  = in_sizes[0] / 64;
    const int M1 = in_sizes[16] / 8;
    const int M3 = in_sizes[18] / 27;

    char* p = (char*)d_ws;
    int* inv3 = (int*)p;                 p += (size_t)28*n_out*4;   // 27 rows + pad row (koff=27)
    int* inv1 = (int*)p;                 p += (size_t)8*n_out*4;
    unsigned short* A = (unsigned short*)p;  p += (size_t)(n_out+1)*64*2;
    unsigned short* B = (unsigned short*)p;  p += (size_t)(n_out+1)*16*2;
    unsigned short* C = (unsigned short*)p;  p += (size_t)(n_out+1)*64*2;
    unsigned short* D = (unsigned short*)p;  p += (size_t)(n_out+1)*16*2;
    unsigned short* E = (unsigned short*)p;  p += (size_t)(n_out+1)*16*2;
    unsigned short* Z = (unsigned short*)p;  p += (size_t)(n_in+2)*64*2;  // +zero row, +pad dump
    unsigned short* Wf_c1 = (unsigned short*)p;  p += (size_t)32*4*512*2;
    unsigned short* Wf_00 = (unsigned short*)p;  p += (size_t)54*512*2;
    unsigned short* Wf_2  = (unsigned short*)p;  p += (size_t)54*512*2;
    unsigned short* Wf_01 = (unsigned short*)p;  p += (size_t)14*2*512*2;
    unsigned short* Wf_11 = (unsigned short*)p;  p += (size_t)14*512*2;
    unsigned short* Wf_10 = (unsigned short*)p;  p += (size_t)2*512*2;
    unsigned short* Wf_12 = (unsigned short*)p;  p += (size_t)2*512*2;
    float* OUT = (float*)d_out;

    auto cdiv = [](long a, long b){ return (int)((a + b - 1)/b); };

    // inv3 sentinel = n_out (A/C zero row); inv1 sentinel = n_in (Z zero row)
    inv_init<<<cdiv((long)28*n_out,256),256,0,stream>>>(inv3, (long)28*n_out, n_out);
    inv_init<<<cdiv((long)8*n_out,256),256,0,stream>>>(inv1, (long)8*n_out, n_in);
    inv_build<<<dim3(cdiv(M3,256),27),256,0,stream>>>(in3, out3, inv3, M3, n_out);
    inv_build<<<dim3(cdiv(M1,256),8),256,0,stream>>>(in1, out1, inv1, M1, n_out);
    zero_rows<<<1,256,0,stream>>>(A, B, C, D, E, Z, n_out, n_in);

    // weight fragment conversion
    wfrag_unpaired<<<cdiv(32*4*512,256),256,0,stream>>>(W1,   Wf_c1, 4, 4, 128, 64, 32*4*512);
    wfrag_unpaired<<<cdiv(54*512,256),  256,0,stream>>>(Wr00, Wf_00, 2, 1,  64, 16, 54*512);
    wfrag_unpaired<<<cdiv(54*512,256),  256,0,stream>>>(W2,   Wf_2,  2, 1,  64,  8, 54*512);
    wfrag_unpaired<<<cdiv(2*512,256),   256,0,stream>>>(Wr10, Wf_10, 2, 1,  64, 16, 2*512);
    wfrag_paired  <<<cdiv(14*2*512,256),256,0,stream>>>(Wr01, Wf_01, 27, 2, 32, 14*2*512);
    wfrag_paired  <<<cdiv(14*512,256),  256,0,stream>>>(Wr11, Wf_11, 27, 1, 16, 14*512);
    wfrag_paired  <<<cdiv(2*512,256),   256,0,stream>>>(Wr12, Wf_12,  1, 2, 32, 2*512);

    // conv1 phase 1 (segment-major grid, hoisted loads, coalesced stores) + phase 2
    conv1_z<<<dim3(8,cdiv(M1,64)),256,0,stream>>>(xF, ctxF, Wf_c1, in1, Z, M1, n_in);
    conv1_sum<<<cdiv((long)8*n_out,256),256,0,stream>>>(Z, inv1, b1, A, n_out);

    const int grid_g = cdiv(n_out, 128);   // paired: 32 rows/wave, 4 waves
    const int grid_l = cdiv(n_out, 64);    // direct gather: 64 rows/block
    const int grid_d = cdiv(n_out, 64);    // dense: 16 rows/wave

    // B = relu(sconv(A, Wr00) + br00)     [W-in-LDS + direct fragment gather]
    gather27_direct<true, true, 16, 16>
        <<<grid_l,256,0,stream>>>(A, Wf_00, inv3, br00, B, n_out);
    // D = relu(A @ Wr10 + br10)
    mfma_dense<2, 1, 128, true, -1, 16, 0, 16>
        <<<grid_d,256,0,stream>>>(A, Wf_10, br10, nullptr, D, n_out);
    // C[:,0:32] = sconv(B, Wr01) + br01 + A[:,0:32]
    mfma_g1<14,7,2, 32, false, 0, 64, 0, 32, 4>
        <<<grid_g,256,0,stream>>>(B, Wf_01, inv3, br01, A, C, n_out);
    // E = relu(sconv(D, Wr11) + br11)
    mfma_g1<14,7,1, 32, true, -1, 16, 0, 16, 4>
        <<<grid_g,256,0,stream>>>(D, Wf_11, inv3, br11, nullptr, E, n_out);
    // C[:,32:64] = E @ Wr12 + br12 + A[:,32:64]
    mfma_dense<3, 2, 32, false, 32, 64, 32, 32>
        <<<grid_d,256,0,stream>>>(E, Wf_12, br12, A, C, n_out);
    // OUT = sconv(C, W2) + b2             [W-in-LDS + direct fragment gather, fp32 out]
    gather27_direct<false, false, 8, 8>
        <<<grid_l,256,0,stream>>>(C, Wf_2, inv3, b2, OUT, n_out);
}

// Round 17
// 262.423 us; speedup vs baseline: 1.4233x; 1.4233x over previous
//
#include <hip/hip_runtime.h>

#define DEV __device__ __forceinline__

typedef __attribute__((ext_vector_type(8))) short bf16x8;
typedef __attribute__((ext_vector_type(4))) float f32x4;

DEV float4 ld4(const float* p){ return *reinterpret_cast<const float4*>(p); }

DEV unsigned short f2bf(float f){
    union { float f; unsigned u; } v; v.f = f;
    unsigned r = v.u + 0x7fffu + ((v.u >> 16) & 1u);   // RNE
    return (unsigned short)(r >> 16);
}
DEV float bf2f(unsigned short s){
    union { unsigned u; float f; } v; v.u = ((unsigned)s) << 16;
    return v.f;
}

// bijective XCD-chunk swizzle (m204)
DEV int xcd_swizzle(int orig, int nwg){
    int q = nwg >> 3, r = nwg & 7;
    int x = orig & 7, i = orig >> 3;
    return (x < r ? x*(q+1) : r*(q+1) + (x-r)*q) + i;
}

// ---------------- inverse kernel-map build ----------------
// one launch: inv3 (28 rows, default n_out) followed by inv1 (8 rows, default n_in)
__global__ __launch_bounds__(256)
void inv_init2(int* __restrict__ base, long n3, long ntot, int d3, int d1){
    long i = (long)blockIdx.x*256 + threadIdx.x;
    if (i < ntot) base[i] = (i < n3) ? d3 : d1;
}

__global__ __launch_bounds__(256)
void inv_build(const int* __restrict__ inK, const int* __restrict__ outK,
               int* __restrict__ inv, int M, int n_out){
    int k = blockIdx.y;
    int m = blockIdx.x*256 + threadIdx.x;
    if (m >= M) return;
    int o = outK[(long)k*M + m];
    if (o != n_out) inv[(long)k*n_out + o] = inK[(long)k*M + m];  // o unique per offset
}

// zero sentinel rows: A/B/C/D/E row n_out; Z row n_in
__global__ __launch_bounds__(256)
void zero_rows(unsigned short* A, unsigned short* B, unsigned short* C,
               unsigned short* D, unsigned short* E, unsigned short* Z,
               int n_out, int n_in){
    int t = threadIdx.x;
    if (t < 64)       A[(long)n_out*64 + t] = 0;
    else if (t < 80)  B[(long)n_out*16 + (t-64)] = 0;
    else if (t < 144) C[(long)n_out*64 + (t-80)] = 0;
    else if (t < 160) D[(long)n_out*16 + (t-144)] = 0;
    else if (t < 176) E[(long)n_out*16 + (t-160)] = 0;
    else if (t < 240) Z[(long)n_in*64 + (t-176)] = 0;
}

// ---------------- W -> fragment-layout bf16 conversion ----------------
__global__ __launch_bounds__(256)
void wfrag_unpaired(const float* __restrict__ W, unsigned short* __restrict__ F,
                    int KC, int NT, int CIN, int CR, int total){
    int idx = blockIdx.x*256 + threadIdx.x;
    if (idx >= total) return;
    int j = idx & 7, l = (idx >> 3) & 63, rest = idx >> 9;
    int nt = rest % NT, cc = rest / NT;
    int k = cc / KC, kc = cc % KC;
    int g = l >> 4, c = l & 15;
    int cin = kc*32 + g*8 + j, cout = nt*16 + c;
    float v = (cout < CR) ? W[((long)k*CIN + cin)*CR + cout] : 0.f;
    F[idx] = f2bf(v);
}

__global__ __launch_bounds__(256)
void wfrag_paired(const float* __restrict__ W, unsigned short* __restrict__ F,
                  int NKr, int NT, int CR, int total){
    int idx = blockIdx.x*256 + threadIdx.x;
    if (idx >= total) return;
    int j = idx & 7, l = (idx >> 3) & 63, rest = idx >> 9;
    int nt = rest % NT, cc = rest / NT;
    int g = l >> 4, c = l & 15;
    int koff = 2*cc + (g >> 1);
    int cin = (g & 1)*8 + j, cout = nt*16 + c;
    float v = (koff < NKr && cout < CR) ? W[((long)koff*16 + cin)*CR + cout] : 0.f;
    F[idx] = f2bf(v);
}

// ---------------- 27-offset gather conv: reg-staged LDS, barrier-free (measured best) ----------
// Block = 4 waves x 16 rows; per-wave private 2KB slices, double-buffered (16KB).
// At the per-CU outstanding-request x L2-latency wall (~12 TB/s of gathered L2 traffic);
// five alternative schedules (barrier-dbuf, vmcnt depth-2/4, 2-per-barrier, W-in-LDS) all
// measured equal or worse.
template<bool RELU, bool OUTBF16, int YS, int CR>
__global__ __launch_bounds__(256)
void gather27_lds(const void* __restrict__ Xv, const unsigned short* __restrict__ Wf,
                  const int* __restrict__ inv, const float* __restrict__ bias,
                  void* __restrict__ Yv, int n_out)
{
    __shared__ alignas(16) char buf[2*8192];
    const int lane = threadIdx.x & 63, w = threadIdx.x >> 6;
    const int bid = xcd_swizzle(blockIdx.x, gridDim.x);
    const long jblock = (long)bid * 64;
    if (jblock >= n_out) return;
    const int r = lane & 15, g = lane >> 4;
    const char* X = (const char*)Xv;
    const bf16x8* __restrict__ WF = (const bf16x8*)Wf;

    const int srow = lane >> 3;                // 0..7
    const int scol = (lane & 7) << 4;          // byte col 0..112
    const long jr0 = min(jblock + w*16 + srow,     (long)n_out - 1);
    const long jr1 = min(jblock + w*16 + 8 + srow, (long)n_out - 1);
    const int wo0 = w*2048 + srow*128     + (scol ^ (srow << 4));
    const int wo1 = w*2048 + (8+srow)*128 + (scol ^ (srow << 4));
    const int ro0 = w*2048 + r*128 + ((     g*16) ^ ((r & 7) << 4));
    const int ro1 = w*2048 + r*128 + ((64 + g*16) ^ ((r & 7) << 4));

    f32x4 acc = {0,0,0,0};

    int i0 = inv[jr0], i1 = inv[jr1];
    float4 f0 = ld4((const float*)(X + (long)i0*128 + scol));
    float4 f1 = ld4((const float*)(X + (long)i1*128 + scol));
    int n0 = inv[(long)n_out + jr0], n1 = inv[(long)n_out + jr1];
    bf16x8 wc0 = WF[lane], wc1 = WF[64 + lane];
    *(float4*)(buf + wo0) = f0;
    *(float4*)(buf + wo1) = f1;

    #pragma unroll 1
    for (int k = 0; k < 27; ++k){
        const int cb = k & 1;
        float4 g0, g1;
        if (k < 26){
            g0 = ld4((const float*)(X + (long)n0*128 + scol));
            g1 = ld4((const float*)(X + (long)n1*128 + scol));
        }
        int t0 = 0, t1 = 0;
        if (k < 25){
            const long ko = (long)(k+2)*n_out;
            t0 = inv[ko + jr0]; t1 = inv[ko + jr1];
        }
        bf16x8 wn0 = wc0, wn1 = wc1;
        if (k < 26){
            wn0 = WF[((long)(k+1)*2    )*64 + lane];
            wn1 = WF[((long)(k+1)*2 + 1)*64 + lane];
        }
        bf16x8 a0 = *(const bf16x8*)(buf + cb*8192 + ro0);
        bf16x8 a1 = *(const bf16x8*)(buf + cb*8192 + ro1);
        acc = __builtin_amdgcn_mfma_f32_16x16x32_bf16(a0, wc0, acc, 0, 0, 0);
        acc = __builtin_amdgcn_mfma_f32_16x16x32_bf16(a1, wc1, acc, 0, 0, 0);
        if (k < 26){
            *(float4*)(buf + (cb^1)*8192 + wo0) = g0;
            *(float4*)(buf + (cb^1)*8192 + wo1) = g1;
        }
        n0 = t0; n1 = t1; wc0 = wn0; wc1 = wn1;
    }

    const float bv = (r < CR) ? bias[r] : 0.f;
    #pragma unroll
    for (int q = 0; q < 4; ++q){
        long row = jblock + w*16 + g*4 + q;
        if (row < n_out){
            float v = acc[q] + bv;
            if constexpr (RELU) v = fmaxf(v, 0.f);
            if constexpr (OUTBF16) ((unsigned short*)Yv)[row*YS + r] = f2bf(v);
            else if (r < CR)       ((float*)Yv)[row*YS + r] = v;
        }
    }
}

// ---------------- conv1 phase 1: Z[i] = x_cat[i] @ W1[kid(i)] — hoisted loads ----------------
__global__ __launch_bounds__(256, 8)
void conv1_z(const float* __restrict__ xF, const float* __restrict__ cF,
             const unsigned short* __restrict__ Wfc1, const int* __restrict__ in1,
             unsigned short* __restrict__ Z, int M1, int n_in)
{
    __shared__ unsigned short tz[4][16*64];
    const int k = blockIdx.x;
    const int lane = threadIdx.x & 63, wave = threadIdx.x >> 6;
    const int m0 = (blockIdx.y*4 + wave)*16;
    if (m0 >= M1) return;
    const int r = lane & 15, g = lane >> 4;
    const int* __restrict__ in1k = in1 + (long)k*M1;
    const int mc = min(m0 + r, M1-1);
    const int i = in1k[mc];
    const bool valid = i < n_in;             // pad sentinel = n_in
    const long iv = valid ? i : 0;
    const bf16x8* __restrict__ WF = (const bf16x8*)(Wfc1 + (size_t)k*16*512);
    const bf16x8 az = {0,0,0,0,0,0,0,0};
    f32x4 acc[4];
    #pragma unroll
    for (int nt=0; nt<4; ++nt) acc[nt] = f32x4{0,0,0,0};

    float4 lo[4], hi[4];
    #pragma unroll
    for (int kc=0; kc<4; ++kc){
        const float* s = (kc < 2) ? (xF + iv*64 + kc*32 + g*8)
                                  : (cF + iv*64 + (kc-2)*32 + g*8);
        lo[kc] = ld4(s);
        hi[kc] = ld4(s+4);
    }
    #pragma unroll
    for (int kc=0; kc<4; ++kc){
        bf16x8 a;
        a[0]=(short)f2bf(lo[kc].x); a[1]=(short)f2bf(lo[kc].y);
        a[2]=(short)f2bf(lo[kc].z); a[3]=(short)f2bf(lo[kc].w);
        a[4]=(short)f2bf(hi[kc].x); a[5]=(short)f2bf(hi[kc].y);
        a[6]=(short)f2bf(hi[kc].z); a[7]=(short)f2bf(hi[kc].w);
        if (!valid) a = az;
        #pragma unroll
        for (int nt=0; nt<4; ++nt){
            bf16x8 wv = WF[((long)kc*4 + nt)*64 + lane];
            acc[nt] = __builtin_amdgcn_mfma_f32_16x16x32_bf16(a, wv, acc[nt], 0, 0, 0);
        }
    }

    #pragma unroll
    for (int q=0; q<4; ++q)
        #pragma unroll
        for (int nt=0; nt<4; ++nt)
            tz[wave][(g*4+q)*64 + nt*16 + r] = f2bf(acc[nt][q]);
    __syncthreads();
    #pragma unroll
    for (int it=0; it<2; ++it){
        int cid = it*64 + lane;
        int row = cid >> 3, c8 = (cid & 7)*8;
        int m = m0 + row;
        if (m < M1){
            int oi = in1k[m];
            long drow = (oi < n_in) ? (long)oi : (long)n_in + 1;
            *(bf16x8*)(Z + drow*64 + c8) = *(const bf16x8*)(&tz[wave][row*64 + c8]);
        }
    }
}

// ---------------- conv1 phase 2: A[o] = b1 + sum_k Z[inv1[k][o]] ----------------
__global__ __launch_bounds__(256)
void conv1_sum(const unsigned short* __restrict__ Z, const int* __restrict__ inv1,
               const float* __restrict__ b1, unsigned short* __restrict__ A, int n_out)
{
    const int bid = xcd_swizzle(blockIdx.x, gridDim.x);
    const long t = (long)bid*256 + threadIdx.x;
    const long o = t >> 3;
    if (o >= n_out) return;
    const int c8 = (int)(t & 7) * 8;
    int b[8];
    #pragma unroll
    for (int k=0;k<8;++k) b[k] = inv1[(long)k*n_out + o];
    float acc[8];
    #pragma unroll
    for (int j=0;j<2;++j){
        float4 v = ld4(b1 + c8 + 4*j);
        acc[4*j]=v.x; acc[4*j+1]=v.y; acc[4*j+2]=v.z; acc[4*j+3]=v.w;
    }
    #pragma unroll
    for (int k=0;k<8;++k){
        bf16x8 z = *(const bf16x8*)(Z + (long)b[k]*64 + c8);
        #pragma unroll
        for (int j=0;j<8;++j) acc[j] += bf2f((unsigned short)z[j]);
    }
    bf16x8 outv;
    #pragma unroll
    for (int j=0;j<8;++j) outv[j] = (short)f2bf(acc[j]);
    *(bf16x8*)(A + o*64 + c8) = outv;
}

// ---------------- paired inv-gather (CIN=16) — validated form ----------------
template<int NK, int G, int NT, int RB, bool RELU, int RESBASE,
         int YS, int CB, int CR, int WPE>
__global__ __launch_bounds__(256, WPE)
void mfma_g1(const void* __restrict__ Xv, const unsigned short* __restrict__ Wf,
             const int* __restrict__ inv, const float* __restrict__ bias,
             const unsigned short* __restrict__ RES, unsigned short* __restrict__ Y, int n_out)
{
    const int lane = threadIdx.x & 63, wave = threadIdx.x >> 6;
    const int jbase = (blockIdx.x*4 + wave)*32;
    if (jbase >= n_out) return;
    const int r = lane & 15, g = lane >> 4;
    const int jc0 = min(jbase + r, n_out-1), jc1 = min(jbase + 16 + r, n_out-1);
    const char* X = (const char*)Xv;
    const bf16x8* __restrict__ WF = (const bf16x8*)Wf;
    f32x4 acc0[NT], acc1[NT];
    #pragma unroll
    for (int nt=0; nt<NT; ++nt){ acc0[nt] = f32x4{0,0,0,0}; acc1[nt] = f32x4{0,0,0,0}; }

    #pragma unroll 1
    for (int g0 = 0; g0 < NK; g0 += G) {
        int b0[G], b1[G];
        #pragma unroll
        for (int kk=0; kk<G; ++kk){
            int koff = 2*(g0+kk) + (g >> 1);
            b0[kk] = inv[(long)koff*n_out + jc0];
            b1[kk] = inv[(long)koff*n_out + jc1];
        }
        #pragma unroll
        for (int kk=0; kk<G; ++kk){
            const int k = g0 + kk;
            bf16x8 a0 = *(const bf16x8*)(X + (long)b0[kk]*RB + (g&1)*16);
            bf16x8 a1 = *(const bf16x8*)(X + (long)b1[kk]*RB + (g&1)*16);
            #pragma unroll
            for (int nt=0; nt<NT; ++nt){
                bf16x8 wv = WF[((long)k*NT + nt)*64 + lane];
                acc0[nt] = __builtin_amdgcn_mfma_f32_16x16x32_bf16(a0, wv, acc0[nt], 0, 0, 0);
                acc1[nt] = __builtin_amdgcn_mfma_f32_16x16x32_bf16(a1, wv, acc1[nt], 0, 0, 0);
            }
        }
    }

    float bi[NT];
    #pragma unroll
    for (int nt=0; nt<NT; ++nt){
        int c = nt*16 + r;
        bi[nt] = (c < CR) ? bias[c] : 0.f;
    }
    #pragma unroll
    for (int q=0; q<4; ++q){
        int row = jbase + g*4 + q;
        if (row < n_out){
            #pragma unroll
            for (int nt=0; nt<NT; ++nt){
                int c = nt*16 + r;
                float v = acc0[nt][q] + bi[nt];
                if constexpr (RESBASE >= 0) v += bf2f(RES[(long)row*64 + RESBASE + c]);
                if constexpr (RELU) v = fmaxf(v, 0.f);
                Y[(long)row*YS + CB + c] = f2bf(v);
            }
        }
        int row2 = jbase + 16 + g*4 + q;
        if (row2 < n_out){
            #pragma unroll
            for (int nt=0; nt<NT; ++nt){
                int c = nt*16 + r;
                float v = acc1[nt][q] + bi[nt];
                if constexpr (RESBASE >= 0) v += bf2f(RES[(long)row2*64 + RESBASE + c]);
                if constexpr (RELU) v = fmaxf(v, 0.f);
                Y[(long)row2*YS + CB + c] = f2bf(v);
            }
        }
    }
}

// ---------------- identity-mode MFMA (dense 1x1s) — validated form ----------------
template<int MODE, int NT, int RB, bool RELU, int RESBASE, int YS, int CB, int CR>
__global__ __launch_bounds__(256)
void mfma_dense(const void* __restrict__ Xv, const unsigned short* __restrict__ Wf,
                const float* __restrict__ bias, const unsigned short* __restrict__ RES,
                unsigned short* __restrict__ Y, int n_out)
{
    const int lane = threadIdx.x & 63, wave = threadIdx.x >> 6;
    const int jbase = (blockIdx.x*4 + wave)*16;
    if (jbase >= n_out) return;
    const int r = lane & 15, g = lane >> 4;
    const int jrow = jbase + r;
    const bool rowok = jrow < n_out;
    const char* X = (const char*)Xv;
    const bf16x8* __restrict__ WF = (const bf16x8*)Wf;
    const bf16x8 az = {0,0,0,0,0,0,0,0};
    f32x4 acc[NT];
    #pragma unroll
    for (int nt=0; nt<NT; ++nt) acc[nt] = f32x4{0,0,0,0};

    if constexpr (MODE == 2) {
        #pragma unroll
        for (int kc=0; kc<2; ++kc){
            bf16x8 a = az;
            if (rowok) a = *(const bf16x8*)(X + (long)jrow*RB + kc*64 + g*16);
            #pragma unroll
            for (int nt=0; nt<NT; ++nt){
                bf16x8 wv = WF[((long)kc*NT + nt)*64 + lane];
                acc[nt] = __builtin_amdgcn_mfma_f32_16x16x32_bf16(a, wv, acc[nt], 0, 0, 0);
            }
        }
    } else {
        bf16x8 a = az;
        if (rowok && g < 2) a = *(const bf16x8*)(X + (long)jrow*RB + (g&1)*16);
        #pragma unroll
        for (int nt=0; nt<NT; ++nt){
            bf16x8 wv = WF[nt*64 + lane];
            acc[nt] = __builtin_amdgcn_mfma_f32_16x16x32_bf16(a, wv, acc[nt], 0, 0, 0);
        }
    }

    float bi[NT];
    #pragma unroll
    for (int nt=0; nt<NT; ++nt){
        int c = nt*16 + r;
        bi[nt] = (c < CR) ? bias[c] : 0.f;
    }
    #pragma unroll
    for (int q=0; q<4; ++q){
        int row = jbase + g*4 + q;
        if (row < n_out){
            #pragma unroll
            for (int nt=0; nt<NT; ++nt){
                int c = nt*16 + r;
                float v = acc[nt][q] + bi[nt];
                if constexpr (RESBASE >= 0) v += bf2f(RES[(long)row*64 + RESBASE + c]);
                if constexpr (RELU) v = fmaxf(v, 0.f);
                Y[(long)row*YS + CB + c] = f2bf(v);
            }
        }
    }
}

extern "C" void kernel_launch(void* const* d_in, const int* in_sizes, int n_in_cnt,
                              void* d_out, int out_size, void* d_ws, size_t ws_size,
                              hipStream_t stream)
{
    const float* xF   = (const float*)d_in[0];
    const float* ctxF = (const float*)d_in[1];
    const float* W1   = (const float*)d_in[2];
    const float* b1   = (const float*)d_in[3];
    const float* Wr00 = (const float*)d_in[4];
    const float* br00 = (const float*)d_in[5];
    const float* Wr01 = (const float*)d_in[6];
    const float* br01 = (const float*)d_in[7];
    const float* Wr10 = (const float*)d_in[8];
    const float* br10 = (const float*)d_in[9];
    const float* Wr11 = (const float*)d_in[10];
    const float* br11 = (const float*)d_in[11];
    const float* Wr12 = (const float*)d_in[12];
    const float* br12 = (const float*)d_in[13];
    const float* W2   = (const float*)d_in[14];
    const float* b2   = (const float*)d_in[15];
    const int* in1  = (const int*)d_in[16];
    const int* out1 = (const int*)d_in[17];
    const int* in3  = (const int*)d_in[18];
    const int* out3 = (const int*)d_in[19];

    const int n_out = out_size / 8;          // CL = 8
    const int n_in  = in_sizes[0] / 64;
    const int M1 = in_sizes[16] / 8;
    const int M3 = in_sizes[18] / 27;

    char* p = (char*)d_ws;
    int* inv3 = (int*)p;                 p += (size_t)28*n_out*4;   // 27 rows + pad row (koff=27)
    int* inv1 = (int*)p;                 p += (size_t)8*n_out*4;    // contiguous after inv3
    unsigned short* A = (unsigned short*)p;  p += (size_t)(n_out+1)*64*2;
    unsigned short* B = (unsigned short*)p;  p += (size_t)(n_out+1)*16*2;
    unsigned short* C = (unsigned short*)p;  p += (size_t)(n_out+1)*64*2;
    unsigned short* D = (unsigned short*)p;  p += (size_t)(n_out+1)*16*2;
    unsigned short* E = (unsigned short*)p;  p += (size_t)(n_out+1)*16*2;
    unsigned short* Z = (unsigned short*)p;  p += (size_t)(n_in+2)*64*2;  // +zero row, +pad dump
    unsigned short* Wf_c1 = (unsigned short*)p;  p += (size_t)32*4*512*2;
    unsigned short* Wf_00 = (unsigned short*)p;  p += (size_t)54*512*2;
    unsigned short* Wf_2  = (unsigned short*)p;  p += (size_t)54*512*2;
    unsigned short* Wf_01 = (unsigned short*)p;  p += (size_t)14*2*512*2;
    unsigned short* Wf_11 = (unsigned short*)p;  p += (size_t)14*512*2;
    unsigned short* Wf_10 = (unsigned short*)p;  p += (size_t)2*512*2;
    unsigned short* Wf_12 = (unsigned short*)p;  p += (size_t)2*512*2;
    float* OUT = (float*)d_out;

    auto cdiv = [](long a, long b){ return (int)((a + b - 1)/b); };

    // sentinel init (single launch): inv3 default n_out, inv1 default n_in
    inv_init2<<<cdiv((long)36*n_out,256),256,0,stream>>>(inv3, (long)28*n_out, (long)36*n_out, n_out, n_in);
    inv_build<<<dim3(cdiv(M3,256),27),256,0,stream>>>(in3, out3, inv3, M3, n_out);
    inv_build<<<dim3(cdiv(M1,256),8),256,0,stream>>>(in1, out1, inv1, M1, n_out);
    zero_rows<<<1,256,0,stream>>>(A, B, C, D, E, Z, n_out, n_in);

    // weight fragment conversion
    wfrag_unpaired<<<cdiv(32*4*512,256),256,0,stream>>>(W1,   Wf_c1, 4, 4, 128, 64, 32*4*512);
    wfrag_unpaired<<<cdiv(54*512,256),  256,0,stream>>>(Wr00, Wf_00, 2, 1,  64, 16, 54*512);
    wfrag_unpaired<<<cdiv(54*512,256),  256,0,stream>>>(W2,   Wf_2,  2, 1,  64,  8, 54*512);
    wfrag_unpaired<<<cdiv(2*512,256),   256,0,stream>>>(Wr10, Wf_10, 2, 1,  64, 16, 2*512);
    wfrag_paired  <<<cdiv(14*2*512,256),256,0,stream>>>(Wr01, Wf_01, 27, 2, 32, 14*2*512);
    wfrag_paired  <<<cdiv(14*512,256),  256,0,stream>>>(Wr11, Wf_11, 27, 1, 16, 14*512);
    wfrag_paired  <<<cdiv(2*512,256),   256,0,stream>>>(Wr12, Wf_12,  1, 2, 32, 2*512);

    // conv1 phase 1 (segment-major grid, hoisted loads, coalesced stores) + phase 2
    conv1_z<<<dim3(8,cdiv(M1,64)),256,0,stream>>>(xF, ctxF, Wf_c1, in1, Z, M1, n_in);
    conv1_sum<<<cdiv((long)8*n_out,256),256,0,stream>>>(Z, inv1, b1, A, n_out);

    const int grid_g = cdiv(n_out, 128);   // paired: 32 rows/wave, 4 waves
    const int grid_l = cdiv(n_out, 64);    // reg-staged gather: 64 rows/block
    const int grid_d = cdiv(n_out, 64);    // dense: 16 rows/wave

    // B = relu(sconv(A, Wr00) + br00)     [reg-staged LDS gather, barrier-free]
    gather27_lds<true, true, 16, 16>
        <<<grid_l,256,0,stream>>>(A, Wf_00, inv3, br00, B, n_out);
    // D = relu(A @ Wr10 + br10)
    mfma_dense<2, 1, 128, true, -1, 16, 0, 16>
        <<<grid_d,256,0,stream>>>(A, Wf_10, br10, nullptr, D, n_out);
    // C[:,0:32] = sconv(B, Wr01) + br01 + A[:,0:32]
    mfma_g1<14,7,2, 32, false, 0, 64, 0, 32, 4>
        <<<grid_g,256,0,stream>>>(B, Wf_01, inv3, br01, A, C, n_out);
    // E = relu(sconv(D, Wr11) + br11)
    mfma_g1<14,7,1, 32, true, -1, 16, 0, 16, 4>
        <<<grid_g,256,0,stream>>>(D, Wf_11, inv3, br11, nullptr, E, n_out);
    // C[:,32:64] = E @ Wr12 + br12 + A[:,32:64]
    mfma_dense<3, 2, 32, false, 32, 64, 32, 32>
        <<<grid_d,256,0,stream>>>(E, Wf_12, br12, A, C, n_out);
    // OUT = sconv(C, W2) + b2             [reg-staged LDS gather, fp32 out masked to 8 cols]
    gather27_lds<false, false, 8, 8>
        <<<grid_l,256,0,stream>>>(C, Wf_2, inv3, b2, OUT, n_out);
}